// Round 5
// baseline (275.542 us; speedup 1.0000x reference)
//
#include <hip/hip_runtime.h>
#include <stdint.h>

#define BB 4
#define SEQ 2048
#define DMODEL 1024
#define NHEAD 16
#define HDIM 64
#define INTER 1024
// attn scale folded into q at GEMM1 epilogue, with log2(e) so softmax is exp2:
// 0.03125 * 1.4426950408889634
#define QSCALE 0.045084220027780106f

#if __has_builtin(__builtin_amdgcn_exp2f)
#define EXP2F(x) __builtin_amdgcn_exp2f(x)
#else
#define EXP2F(x) exp2f(x)
#endif

typedef unsigned short u16;
typedef __attribute__((ext_vector_type(4))) unsigned short u16x4;
typedef __attribute__((ext_vector_type(4))) short s16x4;
typedef __attribute__((ext_vector_type(8))) short s16x8;   // 8 bf16 (4 VGPRs) MFMA A/B frag
typedef __attribute__((ext_vector_type(4))) float f32x4;
typedef __attribute__((ext_vector_type(16))) float f32x16; // 32x32 MFMA C/D frag
typedef __attribute__((ext_vector_type(4))) unsigned int u32x4;

__device__ __forceinline__ u16 f2bf(float f) {
  unsigned int u = __float_as_uint(f);
  u += 0x7FFFu + ((u >> 16) & 1u);   // RNE
  return (u16)(u >> 16);
}

// pack 2 fp32 -> 2 bf16 in one dword (lo = a, hi = b)
#if __has_builtin(__builtin_amdgcn_cvt_pk_bf16_f32)
typedef __attribute__((ext_vector_type(2))) __bf16 bf16x2_t;
__device__ __forceinline__ unsigned int pk2bf(float a, float b) {
  bf16x2_t r = __builtin_amdgcn_cvt_pk_bf16_f32(a, b);
  return *reinterpret_cast<unsigned int*>(&r);
}
#else
__device__ __forceinline__ unsigned int pk2bf(float a, float b) {
  return (unsigned int)f2bf(a) | ((unsigned int)f2bf(b) << 16);
}
#endif

// async global->LDS, 16B per lane; LDS dest is wave-uniform base + lane*16
__device__ __forceinline__ void async16(const u16* g, u16* l) {
  __builtin_amdgcn_global_load_lds((__attribute__((address_space(1))) void*)(void*)(g),
                                   (__attribute__((address_space(3))) void*)(l),
                                   16, 0, 0);
}

// Redistribute P into the two PV B-fragments fully in-register.
// Input per lane (half h, col i=l31): cc[q*2+0] = pk(P[8q+4h+0][i], P[8q+4h+1][i])
//                                     cc[q*2+1] = pk(P[8q+4h+2][i], P[8q+4h+3][i])
// Output: pb0 elem e = P[8h+e][i] (kc=0), pb1 elem e = P[16+8h+e][i] (kc=1).
// v_permlane32_swap(a,b): new_a = {a.row0, b.row0}, new_b = {a.row1, b.row1}
// (vdst.row1 <-> vsrc.row0) -- exactly the cross-half exchange needed.
// Correctness-verified in the harness (absmax identical to the LDS path).
__device__ __forceinline__ void make_pb(const unsigned int* cc, int half,
                                        s16x8& pb0, s16x8& pb1) {
#if __has_builtin(__builtin_amdgcn_permlane32_swap)
  (void)half;
  auto r02 = __builtin_amdgcn_permlane32_swap(cc[0], cc[2], false, false);
  auto r13 = __builtin_amdgcn_permlane32_swap(cc[1], cc[3], false, false);
  auto r46 = __builtin_amdgcn_permlane32_swap(cc[4], cc[6], false, false);
  auto r57 = __builtin_amdgcn_permlane32_swap(cc[5], cc[7], false, false);
  u32x4 w0 = {(unsigned)r02[0], (unsigned)r13[0], (unsigned)r02[1], (unsigned)r13[1]};
  u32x4 w1 = {(unsigned)r46[0], (unsigned)r57[0], (unsigned)r46[1], (unsigned)r57[1]};
#else
  unsigned x0 = __shfl_xor((int)cc[0], 32, 64), x1 = __shfl_xor((int)cc[1], 32, 64);
  unsigned x2 = __shfl_xor((int)cc[2], 32, 64), x3 = __shfl_xor((int)cc[3], 32, 64);
  unsigned x4 = __shfl_xor((int)cc[4], 32, 64), x5 = __shfl_xor((int)cc[5], 32, 64);
  unsigned x6 = __shfl_xor((int)cc[6], 32, 64), x7 = __shfl_xor((int)cc[7], 32, 64);
  u32x4 w0 = {half ? x2 : cc[0], half ? x3 : cc[1],
              half ? cc[2] : x0, half ? cc[3] : x1};
  u32x4 w1 = {half ? x6 : cc[4], half ? x7 : cc[5],
              half ? cc[6] : x4, half ? cc[7] : x5};
#endif
  pb0 = *reinterpret_cast<s16x8*>(&w0);
  pb1 = *reinterpret_cast<s16x8*>(&w1);
}

// ------------- fused prep: cast features + transpose-cast both weights -------------
__global__ __launch_bounds__(256) void prep(
    const float* __restrict__ f, const float* __restrict__ wqkv,
    const float* __restrict__ wout, u16* __restrict__ Xb,
    u16* __restrict__ WqkvT, u16* __restrict__ WoutT) {
  __shared__ float tile[32][33];
  const int bid = blockIdx.x, tid = threadIdx.x;
  if (bid < 8192) {                       // cast features (exactly 8M elements)
    int i = (bid * 256 + tid) * 4;
    f32x4 v = *reinterpret_cast<const f32x4*>(f + i);
    uint2 o;
    o.x = pk2bf(v[0], v[1]);
    o.y = pk2bf(v[2], v[3]);
    *reinterpret_cast<uint2*>(Xb + i) = o;
  } else {                                // transpose-cast a 32x32 tile
    const float* src; u16* dst; int rows, cols, bx, by;
    if (bid < 8192 + 3072) {
      int t = bid - 8192;
      src = wqkv; dst = WqkvT; rows = DMODEL; cols = 3 * INTER;
      bx = t % 96; by = t / 96;
    } else {
      int t = bid - 11264;
      src = wout; dst = WoutT; rows = INTER; cols = DMODEL;
      bx = t & 31; by = t >> 5;
    }
    int c0 = bx * 32, r0 = by * 32, tx = tid & 31, ty = tid >> 5;
    #pragma unroll
    for (int i = ty; i < 32; i += 8) tile[i][tx] = src[(size_t)(r0 + i) * cols + c0 + tx];
    __syncthreads();
    #pragma unroll
    for (int i = ty; i < 32; i += 8)
      dst[(size_t)(c0 + i) * rows + r0 + tx] = f2bf(tile[tx][i]);
  }
}

// ---------------- bf16 GEMM, B-transposed input (m97 structure) ----------------
// MODE 0: q -> Qb row-major (scaled); k -> Kp fragment-packed (base + reg*8
//         stores); v -> Vp fragment-packed (4 regs contiguous -> one b64
//         store). Index math hoisted per-(i,j); region branch wave-uniform.
// MODE 1: C -> fp32 Cf.
template <int MODE>
__global__ __launch_bounds__(256, 2) void gemm_bt(
    const u16* __restrict__ A, const u16* __restrict__ BT,
    float* __restrict__ Cf, u16* __restrict__ Qb, u16* __restrict__ Kp,
    u16* __restrict__ Vp, int K, int ldc) {
  __shared__ u16 As[128 * 32];
  __shared__ u16 Bs[128 * 32];
  const int tid = threadIdx.x;
  const int wave = tid >> 6, lane = tid & 63;
  const int row0 = blockIdx.y * 128, col0 = blockIdx.x * 128;
  const int wr = (wave >> 1) * 64, wc = (wave & 1) * 64;
  const int r = lane & 15, q8 = (lane >> 4) * 8;

  f32x4 acc[4][4] = {};

  const int sRow = lane >> 2, sK = (lane & 3) * 8;
  const u16* Ag0 = A + (size_t)(row0 + wave * 32 + sRow) * K + sK;
  const u16* Ag1 = Ag0 + (size_t)16 * K;
  const u16* Bg0 = BT + (size_t)(col0 + wave * 32 + sRow) * K + sK;
  const u16* Bg1 = Bg0 + (size_t)16 * K;
  u16* Al0 = &As[wave * 1024];
  u16* Al1 = Al0 + 512;
  u16* Bl0 = &Bs[wave * 1024];
  u16* Bl1 = Bl0 + 512;

  for (int k0 = 0; k0 < K; k0 += 32) {
    async16(Ag0 + k0, Al0);
    async16(Ag1 + k0, Al1);
    async16(Bg0 + k0, Bl0);
    async16(Bg1 + k0, Bl1);
    __syncthreads();
    s16x8 af[4], bf[4];
    #pragma unroll
    for (int t = 0; t < 4; t++) {
      af[t] = *reinterpret_cast<const s16x8*>(&As[(wr + t * 16 + r) * 32 + q8]);
      bf[t] = *reinterpret_cast<const s16x8*>(&Bs[(wc + t * 16 + r) * 32 + q8]);
    }
    #pragma unroll
    for (int i = 0; i < 4; i++)
      #pragma unroll
      for (int j = 0; j < 4; j++)
        acc[i][j] = __builtin_amdgcn_mfma_f32_16x16x32_bf16(af[i], bf[j], acc[i][j], 0, 0, 0);
    __syncthreads();
  }

  const int quad = lane >> 4;
  #pragma unroll
  for (int i = 0; i < 4; i++) {
    const int n = row0 + wr + i * 16 + quad * 4;   // global row for regs 0..3
    const int b = n >> 11, nn = n & (SEQ - 1);
    #pragma unroll
    for (int j = 0; j < 4; j++) {
      const int gc = col0 + wc + j * 16 + r;       // wave-uniform region
      if (MODE == 1) {
        #pragma unroll
        for (int reg = 0; reg < 4; reg++)
          Cf[(size_t)(n + reg) * ldc + gc] = acc[i][j][reg];
      } else if (gc < INTER) {                     // q: row-major, scaled
        size_t base = (size_t)n * INTER + gc;
        #pragma unroll
        for (int reg = 0; reg < 4; reg++)
          Qb[base + (size_t)reg * INTER] = f2bf(acc[i][j][reg] * QSCALE);
      } else if (gc < 2 * INTER) {                 // k -> Kp packed
        int dim = gc - INTER, h = dim >> 6, d = dim & 63;
        int bh = b * NHEAD + h;
        size_t base = (((size_t)(bh * 64 + (nn >> 5)) * 4 + (d >> 4)) * 64 +
                       ((((d >> 3) & 1) << 5) | (nn & 31))) * 8 + (d & 7);
        #pragma unroll
        for (int reg = 0; reg < 4; reg++)
          Kp[base + reg * 8] = f2bf(acc[i][j][reg]);
      } else {                                     // v -> Vp packed, b64 store
        int dim = gc - 2 * INTER, h = dim >> 6, d = dim & 63;
        int bh = b * NHEAD + h;
        size_t base = ((((size_t)(bh * 64 + (nn >> 5)) * 2 + ((nn >> 4) & 1)) * 2 +
                        (d >> 5)) * 64 +
                       ((((nn >> 3) & 1) << 5) | (d & 31))) * 8 + (nn & 7);
        uint2 pk;
        pk.x = pk2bf(acc[i][j][0], acc[i][j][1]);
        pk.y = pk2bf(acc[i][j][2], acc[i][j][3]);
        *reinterpret_cast<uint2*>(Vp + base) = pk;
      }
    }
  }
}

// ---------------- flash-style attention, fragment-packed operands ----------------
// grid: (bh=64, iblk=64); blockIdx.x = bh so block->XCD = bh%8 (each XCD owns
// 8 heads = 4 MB K/V in its L2; round-1 proved this mapping must stand).
// One wave per block, 32 q-rows. __launch_bounds__(64,2) -> VGPR cap 256: the
// K+V double-buffered pipeline holds ~170 live regs; (64,3)'s 170 cap would
// risk spill (round-3: spill cost +47 us; WRITE_SIZE is the tell).
//
// T15 pipeline, now 2-deep on BOTH operands (round-4 post-mortem: 42% of wall
// was residual stall; FETCH=49 MB says many K/V loads are L3-served at
// 500-900 cyc, while round-4's V was issued and consumed within one step,
// ~300 cyc of cover -- under-covered):
//   step j: prefetch K(j+2), V(j+1)  (full-step-ahead cover for both)
//           QK: S(j+1) = K(j+1).q    (operands loaded last step)
//           softmax(S(j)) -> pb      (S from last step's QK)
//           PV: ot += V(j).pb        (V loaded last step)
// All loads are [cursor + imm-offset] with two monotonically incremented
// cursors (+2048 elems/step) -- no per-load 64-bit address adds. Tail
// prefetches overrun <=8 KB into the adjacent workspace region (dead data,
// allocated, safe). Static buffer roles (kX/kY, vX/vY, stA/stB) per rule #20.
// S^T = K.Q^T via 32x32x16 MFMA; q pre-scaled by SCALE*log2e -> p = exp2(s);
// no max-shift (scores bounded by construction). No LDS, no barriers; P->PV
// redistribution in-register via v_permlane32_swap. setprio(1) wraps MFMA
// clusters (independent-wave attn regime: m191 +4-7%).
#define PSTEP(SCUR, SNXT, KNXT, KPF, VCUR, VNXT)                                  \
  {                                                                               \
    _Pragma("unroll")                                                             \
    for (int c = 0; c < 4; c++)                                                   \
      KPF[c] = *reinterpret_cast<const s16x8*>(kpf + c * 512);                    \
    _Pragma("unroll")                                                             \
    for (int c = 0; c < 4; c++)                                                   \
      VNXT[c] = *reinterpret_cast<const s16x8*>(vpf + c * 512);                   \
    kpf += 2048;                                                                  \
    vpf += 2048;                                                                  \
    SNXT = (f32x16){};                                                            \
    __builtin_amdgcn_s_setprio(1);                                                \
    _Pragma("unroll")                                                             \
    for (int c = 0; c < 4; c++)                                                   \
      SNXT = __builtin_amdgcn_mfma_f32_32x32x16_bf16(KNXT[c], qf[c], SNXT, 0, 0, 0); \
    __builtin_amdgcn_s_setprio(0);                                                \
    unsigned int cc[8];                                                           \
    _Pragma("unroll")                                                             \
    for (int q = 0; q < 4; q++) {                                                 \
      float p0 = EXP2F(SCUR[q * 4 + 0]), p1 = EXP2F(SCUR[q * 4 + 1]);             \
      float p2 = EXP2F(SCUR[q * 4 + 2]), p3 = EXP2F(SCUR[q * 4 + 3]);             \
      ls += (p0 + p1) + (p2 + p3);                                                \
      cc[q * 2 + 0] = pk2bf(p0, p1);                                              \
      cc[q * 2 + 1] = pk2bf(p2, p3);                                              \
    }                                                                             \
    s16x8 pb0, pb1;                                                               \
    make_pb(cc, half, pb0, pb1);                                                  \
    __builtin_amdgcn_s_setprio(1);                                                \
    ot0 = __builtin_amdgcn_mfma_f32_32x32x16_bf16(VCUR[0], pb0, ot0, 0, 0, 0);    \
    ot1 = __builtin_amdgcn_mfma_f32_32x32x16_bf16(VCUR[1], pb0, ot1, 0, 0, 0);    \
    ot0 = __builtin_amdgcn_mfma_f32_32x32x16_bf16(VCUR[2], pb1, ot0, 0, 0, 0);    \
    ot1 = __builtin_amdgcn_mfma_f32_32x32x16_bf16(VCUR[3], pb1, ot1, 0, 0, 0);    \
    __builtin_amdgcn_s_setprio(0);                                                \
  }

__global__ __launch_bounds__(64, 2) void attn_kernel(
    const u16* __restrict__ Qb, const u16* __restrict__ Kp,
    const u16* __restrict__ Vp, u16* __restrict__ AO) {
  const int lane = threadIdx.x;
  const int l31 = lane & 31, half = lane >> 5;
  const int bh = blockIdx.x, b = bh >> 4, h = bh & 15;
  const int i0 = blockIdx.y * 32;

  // Q fragments (B-operand): B[n=q-row][k=d], k-contiguous. Once per wave.
  const u16* qbase = Qb + (size_t)(b * SEQ + i0 + l31) * INTER + h * HDIM + half * 8;
  s16x8 qf[4];
  #pragma unroll
  for (int c = 0; c < 4; c++) qf[c] = *reinterpret_cast<const s16x8*>(qbase + c * 16);

  const u16* kpf = Kp + (size_t)bh * (64 * 4 * 512) + lane * 8;   // K prefetch cursor
  const u16* vpf = Vp + (size_t)bh * (64 * 4 * 512) + lane * 8;   // V prefetch cursor

  f32x16 ot0 = {}, ot1 = {};
  float ls = 0.f;

  // Pipeline prologue: kX=K(0) -> stA=S(0); kY=K(1); vX=V(0).
  // Cursor state after: kpf -> K(2), vpf -> V(1)  (loop invariant).
  s16x8 kX[4], kY[4], vX[4], vY[4];
  #pragma unroll
  for (int c = 0; c < 4; c++)
    kX[c] = *reinterpret_cast<const s16x8*>(kpf + c * 512);
  kpf += 2048;
  f32x16 stA = {}, stB;
  #pragma unroll
  for (int c = 0; c < 4; c++)
    stA = __builtin_amdgcn_mfma_f32_32x32x16_bf16(kX[c], qf[c], stA, 0, 0, 0);
  #pragma unroll
  for (int c = 0; c < 4; c++)
    kY[c] = *reinterpret_cast<const s16x8*>(kpf + c * 512);
  kpf += 2048;
  #pragma unroll
  for (int c = 0; c < 4; c++)
    vX[c] = *reinterpret_cast<const s16x8*>(vpf + c * 512);
  vpf += 2048;

  // Loop-top invariant (step j): stA=S(j), kY=K(j+1), vX=V(j),
  // kpf->K(j+2), vpf->V(j+1).
  for (int jb = 0; jb < 64; jb += 2) {
    PSTEP(stA, stB, kY, kX, vX, vY)   // S(j) consumed; S(j+1) made; K(j+2)->kX, V(j+1)->vY
    PSTEP(stB, stA, kX, kY, vY, vX)   // S(j+1) consumed; S(j+2) made; K(j+3)->kY, V(j+2)->vX
  }
  // Tail: step 63 consumed S(63) with V(63); its prefetches (K(65), V(64))
  // are dead and overrun <=8 KB into the next workspace region (allocated).

  ls += __shfl_xor(ls, 32, 64);      // lanes L, L+32 hold complementary j-halves
  float rinv = 1.0f / ls;

  u16* orow = AO + (size_t)(b * SEQ + i0 + l31) * INTER + h * HDIM;
  #pragma unroll
  for (int dt = 0; dt < 2; dt++) {
    const f32x16& o = dt ? ot1 : ot0;
    #pragma unroll
    for (int q = 0; q < 4; q++) {
      uint2 pk;
      pk.x = pk2bf(o[q * 4 + 0] * rinv, o[q * 4 + 1] * rinv);
      pk.y = pk2bf(o[q * 4 + 2] * rinv, o[q * 4 + 3] * rinv);
      *reinterpret_cast<uint2*>(orow + dt * 32 + q * 8 + half * 4) = pk;
    }
  }
}

extern "C" void kernel_launch(void* const* d_in, const int* in_sizes, int n_in,
                              void* d_out, int out_size, void* d_ws, size_t ws_size,
                              hipStream_t stream) {
  const float* features = (const float*)d_in[0];
  const float* W_qkv    = (const float*)d_in[1];
  const float* W_out    = (const float*)d_in[2];
  float* out = (float*)d_out;
  char* w = (char*)d_ws;
  u16* Xb    = (u16*)(w);              // [8192][1024] bf16 features      16 MB
  u16* WqkvT = (u16*)(w + 16777216);   // [3072][1024] bf16 W_qkv^T        6 MB
  u16* WoutT = (u16*)(w + 23068672);   // [1024][1024] bf16 W_out^T        2 MB
  u16* Qb    = (u16*)(w + 25165824);   // [8192][1024] bf16 q (scaled)    16 MB
  u16* Kp    = (u16*)(w + 41943040);   // fragment-packed K               16 MB
  u16* Vp    = (u16*)(w + 58720256);   // fragment-packed V               16 MB
  u16* AO    = (u16*)(w + 75497472);   // [8192][1024] bf16 attn out      16 MB

  prep<<<dim3(12288), dim3(256), 0, stream>>>(features, W_qkv, W_out, Xb, WqkvT, WoutT);
  gemm_bt<0><<<dim3(24, 64), dim3(256), 0, stream>>>(Xb, WqkvT, nullptr, Qb, Kp, Vp,
                                                     DMODEL, 0);
  attn_kernel<<<dim3(64, 64), dim3(64), 0, stream>>>(Qb, Kp, Vp, AO);
  gemm_bt<1><<<dim3(8, 64), dim3(256), 0, stream>>>(AO, WoutT, out, nullptr, nullptr,
                                                    nullptr, INTER, DMODEL);
}

// Round 6
// 274.654 us; speedup vs baseline: 1.0032x; 1.0032x over previous
//
#include <hip/hip_runtime.h>
#include <stdint.h>

#define BB 4
#define SEQ 2048
#define DMODEL 1024
#define NHEAD 16
#define HDIM 64
#define INTER 1024
// attn scale folded into q at GEMM1 epilogue, with log2(e) so softmax is exp2:
// 0.03125 * 1.4426950408889634
#define QSCALE 0.045084220027780106f

#if __has_builtin(__builtin_amdgcn_exp2f)
#define EXP2F(x) __builtin_amdgcn_exp2f(x)
#else
#define EXP2F(x) exp2f(x)
#endif

typedef unsigned short u16;
typedef __attribute__((ext_vector_type(4))) unsigned short u16x4;
typedef __attribute__((ext_vector_type(4))) short s16x4;
typedef __attribute__((ext_vector_type(8))) short s16x8;   // 8 bf16 (4 VGPRs) MFMA A/B frag
typedef __attribute__((ext_vector_type(4))) float f32x4;
typedef __attribute__((ext_vector_type(16))) float f32x16; // 32x32 MFMA C/D frag
typedef __attribute__((ext_vector_type(4))) unsigned int u32x4;

__device__ __forceinline__ u16 f2bf(float f) {
  unsigned int u = __float_as_uint(f);
  u += 0x7FFFu + ((u >> 16) & 1u);   // RNE
  return (u16)(u >> 16);
}

// pack 2 fp32 -> 2 bf16 in one dword (lo = a, hi = b)
#if __has_builtin(__builtin_amdgcn_cvt_pk_bf16_f32)
typedef __attribute__((ext_vector_type(2))) __bf16 bf16x2_t;
__device__ __forceinline__ unsigned int pk2bf(float a, float b) {
  bf16x2_t r = __builtin_amdgcn_cvt_pk_bf16_f32(a, b);
  return *reinterpret_cast<unsigned int*>(&r);
}
#else
__device__ __forceinline__ unsigned int pk2bf(float a, float b) {
  return (unsigned int)f2bf(a) | ((unsigned int)f2bf(b) << 16);
}
#endif

// async global->LDS, 16B per lane; LDS dest is wave-uniform base + lane*16
__device__ __forceinline__ void async16(const u16* g, u16* l) {
  __builtin_amdgcn_global_load_lds((__attribute__((address_space(1))) void*)(void*)(g),
                                   (__attribute__((address_space(3))) void*)(l),
                                   16, 0, 0);
}

// Redistribute P into the two PV B-fragments fully in-register.
// Input per lane (half h, col i=l31): cc[q*2+0] = pk(P[8q+4h+0][i], P[8q+4h+1][i])
//                                     cc[q*2+1] = pk(P[8q+4h+2][i], P[8q+4h+3][i])
// Output: pb0 elem e = P[8h+e][i] (kc=0), pb1 elem e = P[16+8h+e][i] (kc=1).
// v_permlane32_swap(a,b): new_a = {a.row0, b.row0}, new_b = {a.row1, b.row1}
// (vdst.row1 <-> vsrc.row0) -- exactly the cross-half exchange needed.
// Correctness-verified in the harness (absmax identical to the LDS path).
__device__ __forceinline__ void make_pb(const unsigned int* cc, int half,
                                        s16x8& pb0, s16x8& pb1) {
#if __has_builtin(__builtin_amdgcn_permlane32_swap)
  (void)half;
  auto r02 = __builtin_amdgcn_permlane32_swap(cc[0], cc[2], false, false);
  auto r13 = __builtin_amdgcn_permlane32_swap(cc[1], cc[3], false, false);
  auto r46 = __builtin_amdgcn_permlane32_swap(cc[4], cc[6], false, false);
  auto r57 = __builtin_amdgcn_permlane32_swap(cc[5], cc[7], false, false);
  u32x4 w0 = {(unsigned)r02[0], (unsigned)r13[0], (unsigned)r02[1], (unsigned)r13[1]};
  u32x4 w1 = {(unsigned)r46[0], (unsigned)r57[0], (unsigned)r46[1], (unsigned)r57[1]};
#else
  unsigned x0 = __shfl_xor((int)cc[0], 32, 64), x1 = __shfl_xor((int)cc[1], 32, 64);
  unsigned x2 = __shfl_xor((int)cc[2], 32, 64), x3 = __shfl_xor((int)cc[3], 32, 64);
  unsigned x4 = __shfl_xor((int)cc[4], 32, 64), x5 = __shfl_xor((int)cc[5], 32, 64);
  unsigned x6 = __shfl_xor((int)cc[6], 32, 64), x7 = __shfl_xor((int)cc[7], 32, 64);
  u32x4 w0 = {half ? x2 : cc[0], half ? x3 : cc[1],
              half ? cc[2] : x0, half ? cc[3] : x1};
  u32x4 w1 = {half ? x6 : cc[4], half ? x7 : cc[5],
              half ? cc[6] : x4, half ? cc[7] : x5};
#endif
  pb0 = *reinterpret_cast<s16x8*>(&w0);
  pb1 = *reinterpret_cast<s16x8*>(&w1);
}

// ------------- fused prep: cast features + transpose-cast both weights -------------
__global__ __launch_bounds__(256) void prep(
    const float* __restrict__ f, const float* __restrict__ wqkv,
    const float* __restrict__ wout, u16* __restrict__ Xb,
    u16* __restrict__ WqkvT, u16* __restrict__ WoutT) {
  __shared__ float tile[32][33];
  const int bid = blockIdx.x, tid = threadIdx.x;
  if (bid < 8192) {                       // cast features (exactly 8M elements)
    int i = (bid * 256 + tid) * 4;
    f32x4 v = *reinterpret_cast<const f32x4*>(f + i);
    uint2 o;
    o.x = pk2bf(v[0], v[1]);
    o.y = pk2bf(v[2], v[3]);
    *reinterpret_cast<uint2*>(Xb + i) = o;
  } else {                                // transpose-cast a 32x32 tile
    const float* src; u16* dst; int rows, cols, bx, by;
    if (bid < 8192 + 3072) {
      int t = bid - 8192;
      src = wqkv; dst = WqkvT; rows = DMODEL; cols = 3 * INTER;
      bx = t % 96; by = t / 96;
    } else {
      int t = bid - 11264;
      src = wout; dst = WoutT; rows = INTER; cols = DMODEL;
      bx = t & 31; by = t >> 5;
    }
    int c0 = bx * 32, r0 = by * 32, tx = tid & 31, ty = tid >> 5;
    #pragma unroll
    for (int i = ty; i < 32; i += 8) tile[i][tx] = src[(size_t)(r0 + i) * cols + c0 + tx];
    __syncthreads();
    #pragma unroll
    for (int i = ty; i < 32; i += 8)
      dst[(size_t)(c0 + i) * rows + r0 + tx] = f2bf(tile[tx][i]);
  }
}

// ---------------- bf16 GEMM, B-transposed input ----------------
// 2-phase double-buffered K-loop (catalog T3-minimum, m248v2 +10%):
// STAGE(t+1) issues BEFORE compute(t) so global->LDS latency hides under the
// MFMAs; one __syncthreads per phase (its implicit vmcnt(0)+lgkmcnt(0) drain
// guarantees the staged buffer is complete and the read buffer is released).
// Hazards: buf written in phase X was last read one barrier earlier; buf read
// in phase X was staged one barrier earlier -- both separated by exactly one
// barrier. K-loop unrolled x2 with static buffer roles (rule #20).
// MODE 0: q -> Qb row-major (scaled); k -> Kp fragment-packed; v -> Vp
//         fragment-packed (b64 store). MODE 1: C -> fp32 Cf.
#define GCOMP(ABUF, BBUF)                                                         \
  {                                                                               \
    s16x8 af[4], bf[4];                                                           \
    _Pragma("unroll")                                                             \
    for (int t = 0; t < 4; t++) {                                                 \
      af[t] = *reinterpret_cast<const s16x8*>(&ABUF[(wr + t * 16 + r) * 32 + q8]); \
      bf[t] = *reinterpret_cast<const s16x8*>(&BBUF[(wc + t * 16 + r) * 32 + q8]); \
    }                                                                             \
    _Pragma("unroll")                                                             \
    for (int i = 0; i < 4; i++)                                                   \
      _Pragma("unroll")                                                           \
      for (int j = 0; j < 4; j++)                                                 \
        acc[i][j] = __builtin_amdgcn_mfma_f32_16x16x32_bf16(af[i], bf[j], acc[i][j], 0, 0, 0); \
  }

template <int MODE>
__global__ __launch_bounds__(256, 2) void gemm_bt(
    const u16* __restrict__ A, const u16* __restrict__ BT,
    float* __restrict__ Cf, u16* __restrict__ Qb, u16* __restrict__ Kp,
    u16* __restrict__ Vp, int K, int ldc) {
  __shared__ u16 As[2][128 * 32];
  __shared__ u16 Bs[2][128 * 32];
  const int tid = threadIdx.x;
  const int wave = tid >> 6, lane = tid & 63;
  const int row0 = blockIdx.y * 128, col0 = blockIdx.x * 128;
  const int wr = (wave >> 1) * 64, wc = (wave & 1) * 64;
  const int r = lane & 15, q8 = (lane >> 4) * 8;

  f32x4 acc[4][4] = {};

  const int sRow = lane >> 2, sK = (lane & 3) * 8;
  const u16* Ag0 = A + (size_t)(row0 + wave * 32 + sRow) * K + sK;
  const u16* Ag1 = Ag0 + (size_t)16 * K;
  const u16* Bg0 = BT + (size_t)(col0 + wave * 32 + sRow) * K + sK;
  const u16* Bg1 = Bg0 + (size_t)16 * K;
  u16* Al0a = &As[0][wave * 1024]; u16* Al1a = Al0a + 512;
  u16* Bl0a = &Bs[0][wave * 1024]; u16* Bl1a = Bl0a + 512;
  u16* Al0b = &As[1][wave * 1024]; u16* Al1b = Al0b + 512;
  u16* Bl0b = &Bs[1][wave * 1024]; u16* Bl1b = Bl0b + 512;

  // prologue: stage K-tile 0 into buffer A
  async16(Ag0, Al0a);
  async16(Ag1, Al1a);
  async16(Bg0, Bl0a);
  async16(Bg1, Bl1a);
  __syncthreads();

  for (int k0 = 0; k0 < K; k0 += 64) {
    // phase A: stage k0+32 -> buf B (overlaps MFMA on buf A)
    if (k0 + 32 < K) {
      async16(Ag0 + k0 + 32, Al0b);
      async16(Ag1 + k0 + 32, Al1b);
      async16(Bg0 + k0 + 32, Bl0b);
      async16(Bg1 + k0 + 32, Bl1b);
    }
    GCOMP(As[0], Bs[0])
    __syncthreads();
    // phase B: stage k0+64 -> buf A (overlaps MFMA on buf B)
    if (k0 + 64 < K) {
      async16(Ag0 + k0 + 64, Al0a);
      async16(Ag1 + k0 + 64, Al1a);
      async16(Bg0 + k0 + 64, Bl0a);
      async16(Bg1 + k0 + 64, Bl1a);
    }
    GCOMP(As[1], Bs[1])
    __syncthreads();
  }

  const int quad = lane >> 4;
  #pragma unroll
  for (int i = 0; i < 4; i++) {
    const int n = row0 + wr + i * 16 + quad * 4;   // global row for regs 0..3
    const int b = n >> 11, nn = n & (SEQ - 1);
    #pragma unroll
    for (int j = 0; j < 4; j++) {
      const int gc = col0 + wc + j * 16 + r;       // wave-uniform region
      if (MODE == 1) {
        #pragma unroll
        for (int reg = 0; reg < 4; reg++)
          Cf[(size_t)(n + reg) * ldc + gc] = acc[i][j][reg];
      } else if (gc < INTER) {                     // q: row-major, scaled
        size_t base = (size_t)n * INTER + gc;
        #pragma unroll
        for (int reg = 0; reg < 4; reg++)
          Qb[base + (size_t)reg * INTER] = f2bf(acc[i][j][reg] * QSCALE);
      } else if (gc < 2 * INTER) {                 // k -> Kp packed
        int dim = gc - INTER, h = dim >> 6, d = dim & 63;
        int bh = b * NHEAD + h;
        size_t base = (((size_t)(bh * 64 + (nn >> 5)) * 4 + (d >> 4)) * 64 +
                       ((((d >> 3) & 1) << 5) | (nn & 31))) * 8 + (d & 7);
        #pragma unroll
        for (int reg = 0; reg < 4; reg++)
          Kp[base + reg * 8] = f2bf(acc[i][j][reg]);
      } else {                                     // v -> Vp packed, b64 store
        int dim = gc - 2 * INTER, h = dim >> 6, d = dim & 63;
        int bh = b * NHEAD + h;
        size_t base = ((((size_t)(bh * 64 + (nn >> 5)) * 2 + ((nn >> 4) & 1)) * 2 +
                        (d >> 5)) * 64 +
                       ((((nn >> 3) & 1) << 5) | (d & 31))) * 8 + (nn & 7);
        uint2 pk;
        pk.x = pk2bf(acc[i][j][0], acc[i][j][1]);
        pk.y = pk2bf(acc[i][j][2], acc[i][j][3]);
        *reinterpret_cast<uint2*>(Vp + base) = pk;
      }
    }
  }
}

// ---------------- flash-style attention, fragment-packed operands ----------------
// ROUND-4 VERSION (best measured: 94.2 us) -- round-5's V-double-buffer was
// neutral-to-negative (97.2) and is reverted.
// grid: (bh=64, iblk=64); blockIdx.x = bh so block->XCD = bh%8 (each XCD owns
// 8 heads = 4 MB K/V in its L2; round-1 proved this mapping must stand).
// One wave per block, 32 q-rows. __launch_bounds__(64,3); ~160 live VGPRs, no
// spill (WRITE_SIZE 16.4 MB is the no-spill tell; round-3's 128-cap spilled).
// T15 pipeline: QK(j+1) issues BEFORE softmax(j) so the MFMA pipe runs under
// the softmax VALU/trans chain; K prefetched 2 steps ahead. Static buffer
// roles (stA/stB, kX/kY) per rule #20; tail recomputes S(0) into the dead
// buffer (4 wasted MFMAs, &63-wrapped in-bounds loads).
// S^T = K.Q^T via 32x32x16 MFMA; q pre-scaled by SCALE*log2e -> p = exp2(s);
// no max-shift (scores bounded by construction). No LDS, no barriers; P->PV
// redistribution in-register via v_permlane32_swap. setprio(1) wraps MFMA
// clusters (independent-wave attn regime: m191 +4-7%).
#define PSTEP(JCUR, SCUR, SNXT, KNXT, KPF)                                        \
  {                                                                               \
    s16x8 vf[4];                                                                  \
    _Pragma("unroll")                                                             \
    for (int c = 0; c < 4; c++)                                                   \
      vf[c] = *reinterpret_cast<const s16x8*>(vpb + (JCUR) * 2048 + c * 512);     \
    const int jpf = ((JCUR) + 2) & 63;                                            \
    _Pragma("unroll")                                                             \
    for (int c = 0; c < 4; c++)                                                   \
      KPF[c] = *reinterpret_cast<const s16x8*>(kpb + jpf * 2048 + c * 512);       \
    SNXT = (f32x16){};                                                            \
    __builtin_amdgcn_s_setprio(1);                                                \
    _Pragma("unroll")                                                             \
    for (int c = 0; c < 4; c++)                                                   \
      SNXT = __builtin_amdgcn_mfma_f32_32x32x16_bf16(KNXT[c], qf[c], SNXT, 0, 0, 0); \
    __builtin_amdgcn_s_setprio(0);                                                \
    unsigned int cc[8];                                                           \
    _Pragma("unroll")                                                             \
    for (int q = 0; q < 4; q++) {                                                 \
      float p0 = EXP2F(SCUR[q * 4 + 0]), p1 = EXP2F(SCUR[q * 4 + 1]);             \
      float p2 = EXP2F(SCUR[q * 4 + 2]), p3 = EXP2F(SCUR[q * 4 + 3]);             \
      ls += (p0 + p1) + (p2 + p3);                                                \
      cc[q * 2 + 0] = pk2bf(p0, p1);                                              \
      cc[q * 2 + 1] = pk2bf(p2, p3);                                              \
    }                                                                             \
    s16x8 pb0, pb1;                                                               \
    make_pb(cc, half, pb0, pb1);                                                  \
    __builtin_amdgcn_s_setprio(1);                                                \
    ot0 = __builtin_amdgcn_mfma_f32_32x32x16_bf16(vf[0], pb0, ot0, 0, 0, 0);      \
    ot1 = __builtin_amdgcn_mfma_f32_32x32x16_bf16(vf[1], pb0, ot1, 0, 0, 0);      \
    ot0 = __builtin_amdgcn_mfma_f32_32x32x16_bf16(vf[2], pb1, ot0, 0, 0, 0);      \
    ot1 = __builtin_amdgcn_mfma_f32_32x32x16_bf16(vf[3], pb1, ot1, 0, 0, 0);      \
    __builtin_amdgcn_s_setprio(0);                                                \
  }

__global__ __launch_bounds__(64, 3) void attn_kernel(
    const u16* __restrict__ Qb, const u16* __restrict__ Kp,
    const u16* __restrict__ Vp, u16* __restrict__ AO) {
  const int lane = threadIdx.x;
  const int l31 = lane & 31, half = lane >> 5;
  const int bh = blockIdx.x, b = bh >> 4, h = bh & 15;
  const int i0 = blockIdx.y * 32;

  // Q fragments (B-operand): B[n=q-row][k=d], k-contiguous. Once per wave.
  const u16* qbase = Qb + (size_t)(b * SEQ + i0 + l31) * INTER + h * HDIM + half * 8;
  s16x8 qf[4];
  #pragma unroll
  for (int c = 0; c < 4; c++) qf[c] = *reinterpret_cast<const s16x8*>(qbase + c * 16);

  const u16* kpb = Kp + (size_t)bh * (64 * 4 * 512) + lane * 8;   // + jblk*2048 + c*512
  const u16* vpb = Vp + (size_t)bh * (64 * 4 * 512) + lane * 8;   // + jblk*2048 + (kc*2+dgrp)*512

  f32x16 ot0 = {}, ot1 = {};
  float ls = 0.f;

  // Pipeline prologue: kX = K(0); stA = S(0); kY = K(1).
  s16x8 kX[4], kY[4];
  #pragma unroll
  for (int c = 0; c < 4; c++)
    kX[c] = *reinterpret_cast<const s16x8*>(kpb + 0 * 2048 + c * 512);
  f32x16 stA = {}, stB;
  #pragma unroll
  for (int c = 0; c < 4; c++)
    stA = __builtin_amdgcn_mfma_f32_32x32x16_bf16(kX[c], qf[c], stA, 0, 0, 0);
  #pragma unroll
  for (int c = 0; c < 4; c++)
    kY[c] = *reinterpret_cast<const s16x8*>(kpb + 1 * 2048 + c * 512);

  // Invariant at loop top: stA = S(j), kY = K(j+1).
  for (int jb = 0; jb < 64; jb += 2) {
    PSTEP(jb,     stA, stB, kY, kX)   // consume S(j);  produce S(j+1); prefetch K(j+2)
    PSTEP(jb + 1, stB, stA, kX, kY)   // consume S(j+1); produce S(j+2); prefetch K(j+3)
  }
  // Tail: final iteration's second PSTEP consumed S(63); the freshly
  // computed stA = S(0)-recompute is dead (4 wasted MFMAs total).

  ls += __shfl_xor(ls, 32, 64);      // lanes L, L+32 hold complementary j-halves
  float rinv = 1.0f / ls;

  u16* orow = AO + (size_t)(b * SEQ + i0 + l31) * INTER + h * HDIM;
  #pragma unroll
  for (int dt = 0; dt < 2; dt++) {
    const f32x16& o = dt ? ot1 : ot0;
    #pragma unroll
    for (int q = 0; q < 4; q++) {
      uint2 pk;
      pk.x = pk2bf(o[q * 4 + 0] * rinv, o[q * 4 + 1] * rinv);
      pk.y = pk2bf(o[q * 4 + 2] * rinv, o[q * 4 + 3] * rinv);
      *reinterpret_cast<uint2*>(orow + dt * 32 + q * 8 + half * 4) = pk;
    }
  }
}

extern "C" void kernel_launch(void* const* d_in, const int* in_sizes, int n_in,
                              void* d_out, int out_size, void* d_ws, size_t ws_size,
                              hipStream_t stream) {
  const float* features = (const float*)d_in[0];
  const float* W_qkv    = (const float*)d_in[1];
  const float* W_out    = (const float*)d_in[2];
  float* out = (float*)d_out;
  char* w = (char*)d_ws;
  u16* Xb    = (u16*)(w);              // [8192][1024] bf16 features      16 MB
  u16* WqkvT = (u16*)(w + 16777216);   // [3072][1024] bf16 W_qkv^T        6 MB
  u16* WoutT = (u16*)(w + 23068672);   // [1024][1024] bf16 W_out^T        2 MB
  u16* Qb    = (u16*)(w + 25165824);   // [8192][1024] bf16 q (scaled)    16 MB
  u16* Kp    = (u16*)(w + 41943040);   // fragment-packed K               16 MB
  u16* Vp    = (u16*)(w + 58720256);   // fragment-packed V               16 MB
  u16* AO    = (u16*)(w + 75497472);   // [8192][1024] bf16 attn out      16 MB

  prep<<<dim3(12288), dim3(256), 0, stream>>>(features, W_qkv, W_out, Xb, WqkvT, WoutT);
  gemm_bt<0><<<dim3(24, 64), dim3(256), 0, stream>>>(Xb, WqkvT, nullptr, Qb, Kp, Vp,
                                                     DMODEL, 0);
  attn_kernel<<<dim3(64, 64), dim3(64), 0, stream>>>(Qb, Kp, Vp, AO);
  gemm_bt<1><<<dim3(8, 64), dim3(256), 0, stream>>>(AO, WoutT, out, nullptr, nullptr,
                                                    nullptr, INTER, DMODEL);
}